// Round 10
// baseline (180.407 us; speedup 1.0000x reference)
//
#include <hip/hip_runtime.h>

// GCN forward: out = PReLU( D^-1/2 (A+I) D^-1/2 (x@W) + b )
// Aggregation commutes with the linear map:
//   xs[i,:] = bf16( dinv[i] * x[i,:] ),  dinv[i] = rsqrt(deg[i]+1)
//   agg[i]  = bf16( dinv[i] * ( xs[i,:] + sum_{s->i} xs[s,:] ) )   (LDS only)
//   out     = PReLU( agg @ W + b )
// R10: k5+k6 fused into K56 — one block per 128-row m-tile computes the
// aggregation straight into the swizzled LDS A-tile (xa buffer deleted),
// then GEMMs all 512 columns with Wt staged in 4 x 32KB chunks (L2-hot).
// Chain: memset -> k1 (hist+fill | prepW) -> k2 (xs) -> K56. 4 dispatches.

typedef __attribute__((ext_vector_type(8))) short bf16x8_t;
typedef __attribute__((ext_vector_type(4))) float f32x4;

#define N_NODES 100000
#define N_EDGES 500000
#define K_IN    128
#define H_OUT   512
#define MAXDEG  32
#define NEB     1954     // ceil(N_EDGES/256)
#define NMT     782      // ceil(N_NODES/128) m-tiles

static __device__ __forceinline__ unsigned short f2b(float f) {
    unsigned u = __float_as_uint(f);
    u = (u + 0x7FFFu + ((u >> 16) & 1u)) >> 16;   // RNE
    return (unsigned short)u;
}
static __device__ __forceinline__ float b2lo(unsigned v) {
    return __uint_as_float(v << 16);
}
static __device__ __forceinline__ float b2hi(unsigned v) {
    return __uint_as_float(v & 0xFFFF0000u);
}

// K1: deg histogram + INLINE padded-CSR fill (atomic old value = slot) | prepW
__global__ __launch_bounds__(256) void k1(const int* __restrict__ ei,
                                          int* __restrict__ deg,
                                          int* __restrict__ csrp,
                                          const float* __restrict__ W,
                                          unsigned short* __restrict__ Wt) {
    int b = blockIdx.x;
    if (b < NEB) {
        int e = b * 256 + threadIdx.x;
        if (e < N_EDGES) {
            int s = ei[e];
            int d = ei[N_EDGES + e];
            int r = atomicAdd(&deg[d], 1);
            csrp[d * MAXDEG + r] = s;
        }
    } else {
        int i = (b - NEB) * 256 + threadIdx.x;   // i = n*128+k
        int n = i >> 7, k = i & 127;
        Wt[i] = f2b(W[k * H_OUT + n]);
    }
}

// K2: xs[i] = bf16( rsqrt(deg+1) * x[i] ) — pure streaming.
__global__ __launch_bounds__(256) void k2(const int* __restrict__ deg,
                                          const float* __restrict__ x,
                                          unsigned* __restrict__ xs) {
    int i = blockIdx.x * 256 + threadIdx.x;      // 0 .. 6.4M-1
    int row = i >> 6;
    float d = rsqrtf((float)(deg[row] + 1));     // broadcast across wave
    const float2* x2 = (const float2*)x;
    float2 xv = x2[i];
    xs[i] = ((unsigned)f2b(d * xv.y) << 16) | f2b(d * xv.x);
}

// K56: fused aggregation + GEMM. One block per 128-row m-tile, 8 waves.
// Phase 1: wave w aggregates nodes [m0+16w, m0+16w+16) into swizzled sA
//          (lane holds one packed dword = 2 features; 64 lanes = full row).
// Phase 2: 4 n-chunks; stage 128x128 Wt chunk into sB (XOR-swizzled),
//          2m x 4n wave grid, 4x2 mfma frags, nontemporal direct stores.
__global__ __launch_bounds__(512) void k56(const unsigned* __restrict__ xs,
                                           const int* __restrict__ csrp,
                                           const int* __restrict__ deg,
                                           const unsigned short* __restrict__ Wt,
                                           const float* __restrict__ bias,
                                           const float* __restrict__ pw,
                                           float* __restrict__ out) {
    __shared__ char smem[65536];
    uint4* sA = (uint4*)smem;              // 32 KB: 128 rows x 16 uint4
    uint4* sB = (uint4*)(smem + 32768);    // 32 KB: one 128-col Wt chunk

    // bijective XCD swizzle for NWG=782: q=97, r=6
    int orig = blockIdx.x;
    int xcd = orig & 7, loc = orig >> 3;
    int wgid = (xcd < 6 ? xcd * 98 : 588 + (xcd - 6) * 97) + loc;
    const int m0 = wgid * 128;
    const int tid = threadIdx.x;
    const int wave = tid >> 6, lane = tid & 63;

    // ---- phase 1: aggregate 16 nodes per wave straight into sA ----
    unsigned* sAd = (unsigned*)smem;
    for (int i = 0; i < 16; ++i) {
        int node = m0 + wave * 16 + i;
        float a0 = 0.f, a1 = 0.f;
        int cnt = 0;
        if (node < N_NODES) {
            unsigned sv = xs[(size_t)node * 64 + lane];
            a0 = b2lo(sv); a1 = b2hi(sv);
            cnt = __builtin_amdgcn_readfirstlane(deg[node]);
            int base = node * MAXDEG;
            for (int j = 0; j < cnt; j += 8) {
                unsigned v[8];
                #pragma unroll
                for (int t = 0; t < 8; ++t) {
                    int valid = (j + t < cnt);
                    int idx = valid ? csrp[base + j + t] : 0;
                    v[t] = valid ? xs[(size_t)idx * 64 + lane] : 0u;
                }
                #pragma unroll
                for (int t = 0; t < 8; ++t) { a0 += b2lo(v[t]); a1 += b2hi(v[t]); }
            }
        }
        float di = rsqrtf((float)(cnt + 1));
        unsigned pk = ((unsigned)f2b(di * a1) << 16) | f2b(di * a0);
        int row = wave * 16 + i;
        int c = lane >> 2;                 // logical uint4 chunk 0..15
        sAd[row * 64 + ((c ^ (row & 7)) << 2) + (lane & 3)] = pk;
    }
    __syncthreads();

    // ---- phase 2: GEMM, 4 n-chunks of 128 columns ----
    const uint4* B4 = (const uint4*)Wt;
    const int wr = wave >> 2, wc = wave & 3;     // 2m x 4n wave grid
    const int l16 = lane & 15, lq = lane >> 4;

    for (int nc = 0; nc < 4; ++nc) {
        // stage B chunk (rows nc*128 .. +127 of Wt[512][128])
        #pragma unroll
        for (int r = 0; r < 4; ++r) {
            int i = tid + r * 512;
            int row = i >> 4, c = i & 15;
            sB[row * 16 + (c ^ (row & 7))] = B4[(size_t)(nc * 128 + row) * 16 + c];
        }
        __syncthreads();

        f32x4 acc[4][2];
        #pragma unroll
        for (int m = 0; m < 4; ++m)
            #pragma unroll
            for (int n = 0; n < 2; ++n)
                acc[m][n] = (f32x4){0.f, 0.f, 0.f, 0.f};

        #pragma unroll
        for (int kk = 0; kk < 4; ++kk) {
            bf16x8_t av[4], bv[2];
            #pragma unroll
            for (int m = 0; m < 4; ++m) {
                int row = wr * 64 + m * 16 + l16;
                av[m] = __builtin_bit_cast(bf16x8_t, sA[row * 16 + ((kk * 4 + lq) ^ (row & 7))]);
            }
            #pragma unroll
            for (int n = 0; n < 2; ++n) {
                int row = wc * 32 + n * 16 + l16;
                bv[n] = __builtin_bit_cast(bf16x8_t, sB[row * 16 + ((kk * 4 + lq) ^ (row & 7))]);
            }
            #pragma unroll
            for (int m = 0; m < 4; ++m)
                #pragma unroll
                for (int n = 0; n < 2; ++n)
                    acc[m][n] = __builtin_amdgcn_mfma_f32_16x16x32_bf16(av[m], bv[n], acc[m][n], 0, 0, 0);
        }

        // epilogue: bias + PReLU, nontemporal direct stores
        float bn[2], pn[2];
        #pragma unroll
        for (int n = 0; n < 2; ++n) {
            int gn = nc * 128 + wc * 32 + n * 16 + l16;
            bn[n] = bias[gn];
            pn[n] = pw[gn];
        }
        #pragma unroll
        for (int m = 0; m < 4; ++m) {
            #pragma unroll
            for (int r = 0; r < 4; ++r) {
                int gm = m0 + wr * 64 + m * 16 + lq * 4 + r;
                if (gm < N_NODES) {
                    #pragma unroll
                    for (int n = 0; n < 2; ++n) {
                        int gn = nc * 128 + wc * 32 + n * 16 + l16;
                        float t = acc[m][n][r] + bn[n];
                        float v = t >= 0.f ? t : pn[n] * t;
                        __builtin_nontemporal_store(v, &out[(size_t)gm * H_OUT + gn]);
                    }
                }
            }
        }
        __syncthreads();   // sB reads done before restage (stores don't use LDS)
    }
}

extern "C" void kernel_launch(void* const* d_in, const int* in_sizes, int n_in,
                              void* d_out, int out_size, void* d_ws, size_t ws_size,
                              hipStream_t stream) {
    const float* x    = (const float*)d_in[0];
    const int*   ei   = (const int*)d_in[1];
    const float* W    = (const float*)d_in[2];
    const float* bias = (const float*)d_in[3];
    const float* pw   = (const float*)d_in[4];
    float* out = (float*)d_out;

    char* ws = (char*)d_ws;
    size_t off = 0;
    auto alloc = [&](size_t bytes) -> void* {
        void* p = ws + off;
        off += (bytes + 255) & ~(size_t)255;
        return p;
    };
    unsigned*       xs   = (unsigned*)alloc((size_t)N_NODES * K_IN * 2);       // 25.6 MB
    unsigned short* Wt   = (unsigned short*)alloc((size_t)K_IN * H_OUT * 2);   // 131 KB
    int*            deg  = (int*)alloc((size_t)N_NODES * 4);                   // 400 KB
    int*            csrp = (int*)alloc((size_t)N_NODES * MAXDEG * 4);          // 12.8 MB
    (void)ws_size; (void)in_sizes; (void)n_in; (void)out_size;

    hipMemsetAsync(deg, 0, (size_t)N_NODES * 4, stream);

    k1 <<<NEB + 256, 256, 0, stream>>>(ei, deg, csrp, W, Wt);
    k2 <<<25000, 256, 0, stream>>>(deg, x, xs);
    k56<<<NMT, 512, 0, stream>>>(xs, csrp, deg,
                                 (const unsigned short*)Wt, bias, pw, out);
}

// Round 11
// 145.306 us; speedup vs baseline: 1.2416x; 1.2416x over previous
//
#include <hip/hip_runtime.h>

// GCN forward: out = PReLU( D^-1/2 (A+I) D^-1/2 (x@W) + b )
// Aggregation commutes with the linear map:
//   xs[i,:] = bf16( dinv[i] * x[i,:] ),  dinv[i] = rsqrt(deg[i]+1)
//   xa[i,:] = bf16( dinv[i] * ( xs[i,:] + sum_{s->i} xs[s,:] ) )
//   out     = PReLU( xa @ W + b )
// R11 = R9 structure (R10's fusion regressed: gather needs TLP) with k5's
// dependency chain shortened: int4 adjacency loads (2 instead of 8 scalar),
// unconditional clamped gathers with value-masking (no per-edge branches).

typedef __attribute__((ext_vector_type(8))) short bf16x8_t;
typedef __attribute__((ext_vector_type(4))) float f32x4;

#define N_NODES 100000
#define N_EDGES 500000
#define K_IN    128
#define H_OUT   512
#define MAXDEG  32
#define NEB     1954     // ceil(N_EDGES/256)

static __device__ __forceinline__ unsigned short f2b(float f) {
    unsigned u = __float_as_uint(f);
    u = (u + 0x7FFFu + ((u >> 16) & 1u)) >> 16;   // RNE
    return (unsigned short)u;
}
static __device__ __forceinline__ float b2lo(unsigned v) {
    return __uint_as_float(v << 16);
}
static __device__ __forceinline__ float b2hi(unsigned v) {
    return __uint_as_float(v & 0xFFFF0000u);
}

// K1: deg histogram + INLINE padded-CSR fill (atomic old value = slot) | prepW
__global__ __launch_bounds__(256) void k1(const int* __restrict__ ei,
                                          int* __restrict__ deg,
                                          int* __restrict__ csrp,
                                          const float* __restrict__ W,
                                          unsigned short* __restrict__ Wt) {
    int b = blockIdx.x;
    if (b < NEB) {
        int e = b * 256 + threadIdx.x;
        if (e < N_EDGES) {
            int s = ei[e];
            int d = ei[N_EDGES + e];
            int r = atomicAdd(&deg[d], 1);
            csrp[d * MAXDEG + r] = s;
        }
    } else {
        int i = (b - NEB) * 256 + threadIdx.x;   // i = n*128+k
        int n = i >> 7, k = i & 127;
        Wt[i] = f2b(W[k * H_OUT + n]);
    }
}

// K2: xs[i] = bf16( rsqrt(deg+1) * x[i] ) — pure streaming.
__global__ __launch_bounds__(256) void k2(const int* __restrict__ deg,
                                          const float* __restrict__ x,
                                          unsigned* __restrict__ xs) {
    int i = blockIdx.x * 256 + threadIdx.x;      // 0 .. 6.4M-1
    int row = i >> 6;
    float d = rsqrtf((float)(deg[row] + 1));     // broadcast across wave
    const float2* x2 = (const float2*)x;
    float2 xv = x2[i];
    xs[i] = ((unsigned)f2b(d * xv.y) << 16) | f2b(d * xv.x);
}

// K5: xa[i] = bf16( dinv[i] * (xs[i] + sum_{s->i} xs[s]) ), 1 wave/node.
// Adjacency row fetched as int4 pairs (2 loads, not 8); gathers issued
// UNCONDITIONALLY with clamped indices (pad slots hold 0xAA poison -> clamp
// to 0), masked at the accumulate. Keeps 8 gathers in flight, no branches.
__global__ __launch_bounds__(256) void k5(const unsigned* __restrict__ xs,
                                          const int* __restrict__ csrp,
                                          const int* __restrict__ deg,
                                          unsigned* __restrict__ xa) {
    int wave = threadIdx.x >> 6, lane = threadIdx.x & 63;
    int node = blockIdx.x * 4 + wave;
    if (node >= N_NODES) return;

    unsigned sv = xs[(size_t)node * 64 + lane];
    int cnt = __builtin_amdgcn_readfirstlane(deg[node]);
    float a0 = b2lo(sv), a1 = b2hi(sv);

    const int4* cp = (const int4*)(csrp + node * MAXDEG);
    for (int j = 0; j < cnt; j += 8) {
        int4 ca = cp[(j >> 2)];
        int4 cb = cp[(j >> 2) + 1];
        unsigned idx[8] = {(unsigned)ca.x, (unsigned)ca.y, (unsigned)ca.z, (unsigned)ca.w,
                           (unsigned)cb.x, (unsigned)cb.y, (unsigned)cb.z, (unsigned)cb.w};
        unsigned v[8];
        #pragma unroll
        for (int t = 0; t < 8; ++t) {
            unsigned id = idx[t] < N_NODES ? idx[t] : 0u;   // clamp poison
            v[t] = xs[(size_t)id * 64 + lane];
        }
        int rem = cnt - j;   // wave-uniform
        #pragma unroll
        for (int t = 0; t < 8; ++t) {
            unsigned val = (t < rem) ? v[t] : 0u;
            a0 += b2lo(val);
            a1 += b2hi(val);
        }
    }
    float di = rsqrtf((float)(cnt + 1));
    xa[(size_t)node * 64 + lane] = ((unsigned)f2b(di * a1) << 16) | f2b(di * a0);
}

// K6: out = PReLU(xa @ W + b). Each block: one 128-col B tile staged once,
// TWO 128-row m-tiles computed against it. 4 waves (2x2), wave = 64x64 via
// 4x4 mfma 16x16x32 bf16. XOR-swizzled LDS staging; epilogue via LDS
// (aliased over the dead sA region, stride 128) + nontemporal f32x4 stores.
// Grid 1564 = 4 n-tiles x 391 m-pairs; bijective q/r XCD swizzle (q=195,r=4).
__global__ __launch_bounds__(256) void k6(const unsigned short* __restrict__ xa,
                                          const unsigned short* __restrict__ Wt,
                                          const float* __restrict__ bias,
                                          const float* __restrict__ pw,
                                          float* __restrict__ out) {
    __shared__ char smem[65536];
    uint4* sA = (uint4*)smem;              // 32 KB
    uint4* sB = (uint4*)(smem + 32768);    // 32 KB (persists across m-tiles)
    float* ep = (float*)smem;              // epilogue alias over sA: 64x128 f32

    // bijective XCD swizzle for NWG=1564: q=195, r=4
    int orig = blockIdx.x;
    int xcd = orig & 7, loc = orig >> 3;
    int wgid = (xcd < 4 ? xcd * 196 : 784 + (xcd - 4) * 195) + loc;
    const int n0 = (wgid & 3) * 128;
    const int mpair = wgid >> 2;           // 0..390
    const int tid = threadIdx.x;

    const uint4* A4 = (const uint4*)xa;
    const uint4* B4 = (const uint4*)Wt;

    // stage B once
    #pragma unroll
    for (int r = 0; r < 8; ++r) {
        int i = tid + r * 256;
        int row = i >> 4, c = i & 15;
        sB[row * 16 + (c ^ (row & 7))] = B4[(size_t)(n0 + row) * 16 + c];
    }

    const int lane = tid & 63, wave = tid >> 6;
    const int wr = wave >> 1, wc = wave & 1;
    const int l16 = lane & 15, lq = lane >> 4;

    float bn[4], pn[4];
    #pragma unroll
    for (int n = 0; n < 4; ++n) {
        int gn = n0 + wc * 64 + n * 16 + l16;
        bn[n] = bias[gn];
        pn[n] = pw[gn];
    }

    for (int half = 0; half < 2; ++half) {
        const int m0 = (mpair * 2 + half) * 128;

        // stage A for this m-tile (sA region is free here)
        #pragma unroll
        for (int r = 0; r < 8; ++r) {
            int i = tid + r * 256;
            int row = i >> 4, c = i & 15;
            int grow = m0 + row;
            uint4 o = (grow < N_NODES) ? A4[(size_t)grow * 16 + c]
                                       : make_uint4(0u, 0u, 0u, 0u);
            sA[row * 16 + (c ^ (row & 7))] = o;
        }
        __syncthreads();   // A (and B on first pass) visible

        f32x4 acc[4][4];
        #pragma unroll
        for (int m = 0; m < 4; ++m)
            #pragma unroll
            for (int n = 0; n < 4; ++n)
                acc[m][n] = (f32x4){0.f, 0.f, 0.f, 0.f};

        #pragma unroll
        for (int kk = 0; kk < 4; ++kk) {
            bf16x8_t av[4], bv[4];
            #pragma unroll
            for (int m = 0; m < 4; ++m) {
                int row = wr * 64 + m * 16 + l16;
                av[m] = __builtin_bit_cast(bf16x8_t, sA[row * 16 + ((kk * 4 + lq) ^ (row & 7))]);
            }
            #pragma unroll
            for (int n = 0; n < 4; ++n) {
                int row = wc * 64 + n * 16 + l16;
                bv[n] = __builtin_bit_cast(bf16x8_t, sB[row * 16 + ((kk * 4 + lq) ^ (row & 7))]);
            }
            #pragma unroll
            for (int m = 0; m < 4; ++m)
                #pragma unroll
                for (int n = 0; n < 4; ++n)
                    acc[m][n] = __builtin_amdgcn_mfma_f32_16x16x32_bf16(av[m], bv[n], acc[m][n], 0, 0, 0);
        }
        __syncthreads();   // all sA reads done before ep overwrites it

        // epilogue: two 64-row sub-phases through ep (stride 128, over sA)
        #pragma unroll
        for (int h = 0; h < 2; ++h) {
            if (wr == h) {
                #pragma unroll
                for (int m = 0; m < 4; ++m)
                    #pragma unroll
                    for (int r = 0; r < 4; ++r) {
                        int row = m * 16 + lq * 4 + r;
                        #pragma unroll
                        for (int n = 0; n < 4; ++n) {
                            float t = acc[m][n][r] + bn[n];
                            float v = t >= 0.f ? t : pn[n] * t;
                            ep[row * 128 + wc * 64 + n * 16 + l16] = v;
                        }
                    }
            }
            __syncthreads();
            #pragma unroll
            for (int it = 0; it < 8; ++it) {
                int row = it * 8 + (tid >> 5);
                int gm = m0 + h * 64 + row;
                if (gm < N_NODES) {
                    int c4 = tid & 31;
                    f32x4 v = *(const f32x4*)&ep[row * 128 + c4 * 4];
                    __builtin_nontemporal_store(v, (f32x4*)&out[(size_t)gm * H_OUT + n0 + c4 * 4]);
                }
            }
            __syncthreads();   // ep reads done before next write phase / A stage
        }
    }
}

extern "C" void kernel_launch(void* const* d_in, const int* in_sizes, int n_in,
                              void* d_out, int out_size, void* d_ws, size_t ws_size,
                              hipStream_t stream) {
    const float* x    = (const float*)d_in[0];
    const int*   ei   = (const int*)d_in[1];
    const float* W    = (const float*)d_in[2];
    const float* bias = (const float*)d_in[3];
    const float* pw   = (const float*)d_in[4];
    float* out = (float*)d_out;

    char* ws = (char*)d_ws;
    size_t off = 0;
    auto alloc = [&](size_t bytes) -> void* {
        void* p = ws + off;
        off += (bytes + 255) & ~(size_t)255;
        return p;
    };
    unsigned*       xs   = (unsigned*)alloc((size_t)N_NODES * K_IN * 2);       // 25.6 MB
    unsigned*       xa   = (unsigned*)alloc((size_t)N_NODES * K_IN * 2);       // 25.6 MB
    unsigned short* Wt   = (unsigned short*)alloc((size_t)K_IN * H_OUT * 2);   // 131 KB
    int*            deg  = (int*)alloc((size_t)N_NODES * 4);                   // 400 KB
    int*            csrp = (int*)alloc((size_t)N_NODES * MAXDEG * 4);          // 12.8 MB
    (void)ws_size; (void)in_sizes; (void)n_in; (void)out_size;

    hipMemsetAsync(deg, 0, (size_t)N_NODES * 4, stream);

    k1 <<<NEB + 256, 256, 0, stream>>>(ei, deg, csrp, W, Wt);
    k2 <<<25000, 256, 0, stream>>>(deg, x, xs);
    k5 <<<(N_NODES + 3) / 4, 256, 0, stream>>>(xs, csrp, deg, xa);
    k6 <<<1564, 256, 0, stream>>>((const unsigned short*)xa,
                                  (const unsigned short*)Wt, bias, pw, out);
}